// Round 5
// baseline (406.499 us; speedup 1.0000x reference)
//
#include <hip/hip_runtime.h>

// Problem constants
#define B_N    64
#define S_LEN  1024
#define EMB    300
#define EMB_P  304              // padded token stride (halves) -> 608B, 16B-aligned
#define NGRAM  5
#define WPAD   1024             // windows per batch padded 1020 -> 1024
#define MTOT   (B_N * WPAD)     // 65536 rows
#define K1P    1536             // padded K for layer 1 (5*304 = 1520 -> 1536)
#define H0     512
#define H1D    256
#define H2D    128

#define GATHER_BLOCKS ((MTOT * (EMB_P / 4)) / 256)   // 19456
#define WPREP_THREADS (H0 * K1P + H1D * H0 + H2D * H1D)
#define WPREP_BLOCKS  ((WPREP_THREADS + 255) / 256)

typedef _Float16 half8 __attribute__((ext_vector_type(8)));
typedef float  floatx4 __attribute__((ext_vector_type(4)));

// ------------- fused prep: gather table[x]->fp16, weight transpose, zero out
// Weights go to FRAGMENT-MAJOR layout so GEMM B-frag loads are coalesced:
//   Bf[((n16*nK + kstep)*64 + quad*16 + l16)*8 + c] = B^T[n16*16+l16][kstep*32+quad*8+c]
__global__ void prep_kernel(const int* __restrict__ x,
                            const float* __restrict__ table,
                            _Float16* __restrict__ emb,
                            float* __restrict__ out,
                            const float* __restrict__ Ws,
                            const float* __restrict__ W1,
                            const float* __restrict__ W2,
                            _Float16* __restrict__ Bf1,
                            _Float16* __restrict__ Bf2,
                            _Float16* __restrict__ Bf3) {
  const int bid = blockIdx.x;
  if (bid < GATHER_BLOCKS) {
    if (bid < 32) out[bid * 256 + threadIdx.x] = 0.0f;  // zero 8192 outputs
    const int CH = EMB_P / 4;  // 76
    int tid = bid * 256 + threadIdx.x;
    int tok = tid / CH;
    int c   = tid - tok * CH;
    int e   = c << 2;
    _Float16 h0, h1, h2, h3;
    if (e < EMB) {
      float4 v = *(const float4*)(table + (size_t)x[tok] * EMB + e);
      h0 = (_Float16)v.x; h1 = (_Float16)v.y; h2 = (_Float16)v.z; h3 = (_Float16)v.w;
    } else {
      h0 = h1 = h2 = h3 = (_Float16)0.0f;
    }
    union { float2 f2; _Float16 h[4]; } u;
    u.h[0] = h0; u.h[1] = h1; u.h[2] = h2; u.h[3] = h3;
    *(float2*)(emb + (size_t)tok * EMB_P + e) = u.f2;
  } else {
    int tid = (bid - GATHER_BLOCKS) * 256 + threadIdx.x;
    const int NS = H0 * K1P;
    const int N1 = H1D * H0;
    const int N2 = H2D * H1D;
    if (tid < NS) {                 // layer1: n in [512), k in [1536), nK=48
      int n = tid / K1P, k = tid - n * K1P;
      float v = 0.0f;
      if (k < NGRAM * EMB_P) {
        int tn = k / EMB_P, e = k - tn * EMB_P;
        if (e < EMB) v = Ws[(size_t)(tn * EMB + e) * H0 + n];
      }
      int idx = ((((n >> 4) * 48 + (k >> 5)) << 6) + (((k >> 3) & 3) << 4) + (n & 15)) * 8 + (k & 7);
      Bf1[idx] = (_Float16)v;
    } else if (tid < NS + N1) {     // layer2: n in [256), k in [512), nK=16
      int t = tid - NS;
      int n = t / H0, k = t - n * H0;
      float v = W1[(size_t)k * H1D + n];
      int idx = ((((n >> 4) * 16 + (k >> 5)) << 6) + (((k >> 3) & 3) << 4) + (n & 15)) * 8 + (k & 7);
      Bf2[idx] = (_Float16)v;
    } else if (tid < NS + N1 + N2) {  // layer3: n in [128), k in [256), nK=8
      int t = tid - (NS + N1);
      int n = t / H1D, k = t - n * H1D;
      float v = W2[(size_t)k * H2D + n];
      int idx = ((((n >> 4) * 8 + (k >> 5)) << 6) + (((k >> 3) & 3) << 4) + (n & 15)) * 8 + (k & 7);
      Bf3[idx] = (_Float16)v;
    }
  }
}

// ------------------------------------------------------------ NT MFMA GEMM
// C[M,N] = A[M,K] @ B[K,N], 128x128 tile, 4 waves (2x2, 64x64 each), fp16
// MFMA 16x16x32. NO LDS, NO K-loop barriers: A frags read strided from
// global (L1/L2-resident), B frags read coalesced from fragment-major Bf.
// Latency hidden by occupancy + compiler load scheduling across unrolls.
// XCD-affine block swizzle keeps A-tile siblings on one XCD's L2.
// EPI 0: +bias, store fp16.  EPI 1: +bias, relu, store fp16.
// EPI 2: +bias, relu, masked-mean pooling via atomics (N=128, one tile).
template <int EPI>
__global__ __launch_bounds__(256, 3)
void gemm_nt(const _Float16* __restrict__ A, const _Float16* __restrict__ Bf,
             const float* __restrict__ bias, _Float16* __restrict__ C,
             float* __restrict__ out, const int* __restrict__ lengths,
             int N, int K, int lda, int nTiles) {
  const int tid  = threadIdx.x;
  const int wave = tid >> 6;
  const int lane = tid & 63;
  const int wr   = wave >> 1, wc = wave & 1;
  const int quad = lane >> 4, l16 = lane & 15;

  const int perX = gridDim.x >> 3;
  const int L    = (blockIdx.x & 7) * perX + (blockIdx.x >> 3);
  const int mt = L / nTiles;
  const int nt = L - mt * nTiles;
  const long mBase = (long)mt << 7;
  const int  nBase = nt << 7;
  const int  nK   = K >> 5;

  // A fragment row pointers: row = mBase + wr*64 + i*16 + l16, k-off quad*8
  const _Float16* aR[4];
#pragma unroll
  for (int i = 0; i < 4; i++)
    aR[i] = A + (mBase + (wr << 6) + (i << 4) + l16) * lda + (quad << 3);
  // B fragment pointers (coalesced 1KB per load): n16 = nBase/16 + wc*4 + j
  const _Float16* bR[4];
#pragma unroll
  for (int j = 0; j < 4; j++)
    bR[j] = Bf + ((size_t)(((nBase >> 4) + (wc << 2) + j) * nK) << 9) + (lane << 3);

  floatx4 acc[4][4] = {};

#pragma unroll 2
  for (int kk = 0; kk < nK; kk++) {
    half8 aF[4], bF[4];
    const int ko = kk << 5;
#pragma unroll
    for (int i = 0; i < 4; i++) aF[i] = *(const half8*)(aR[i] + ko);
#pragma unroll
    for (int j = 0; j < 4; j++) bF[j] = *(const half8*)(bR[j] + ((size_t)kk << 9));
#pragma unroll
    for (int i = 0; i < 4; i++)
#pragma unroll
      for (int j = 0; j < 4; j++)
        acc[i][j] = __builtin_amdgcn_mfma_f32_16x16x32_f16(aF[i], bF[j], acc[i][j], 0, 0, 0);
  }

  if constexpr (EPI < 2) {
#pragma unroll
    for (int j = 0; j < 4; j++) {
      int col = nBase + (wc << 6) + (j << 4) + l16;
      float bv = bias[col];
#pragma unroll
      for (int i = 0; i < 4; i++) {
        long row = mBase + (wr << 6) + (i << 4) + (quad << 2);
#pragma unroll
        for (int r = 0; r < 4; r++) {
          float v = acc[i][j][r] + bv;
          if (EPI == 1) v = fmaxf(v, 0.0f);
          C[(size_t)(row + r) * N + col] = (_Float16)v;
        }
      }
    }
  } else {
    // fused relu + ragged-mean pooling. 1024 rows/batch = 8 tiles: whole
    // block is one batch. C/D layout: col = lane&15, row = quad*4 + reg.
    __shared__ float red[2][128];
    int b = mt >> 3;
    int validw = lengths[b] - (NGRAM - 1);
    float inv = 1.0f / (float)validw;
    int wBase = ((mt & 7) << 7) + (wr << 6);
#pragma unroll
    for (int j = 0; j < 4; j++) {
      int col = (wc << 6) + (j << 4) + l16;
      float bv = bias[col];
      float p = 0.0f;
#pragma unroll
      for (int i = 0; i < 4; i++) {
#pragma unroll
        for (int r = 0; r < 4; r++) {
          int w = wBase + (i << 4) + (quad << 2) + r;
          float v = fmaxf(acc[i][j][r] + bv, 0.0f);
          p += (w < validw) ? v : 0.0f;
        }
      }
      p *= inv;
      p += __shfl_xor(p, 16, 64);
      p += __shfl_xor(p, 32, 64);
      if (quad == 0) red[wr][col] = p;
    }
    __syncthreads();
    if (tid < 128) atomicAdd(out + b * H2D + tid, red[0][tid] + red[1][tid]);
  }
}

// ---------------------------------------------------------------- launcher
extern "C" void kernel_launch(void* const* d_in, const int* in_sizes, int n_in,
                              void* d_out, int out_size, void* d_ws, size_t ws_size,
                              hipStream_t stream) {
  const int*   x       = (const int*)d_in[0];
  const int*   lengths = (const int*)d_in[1];
  const float* table   = (const float*)d_in[2];
  const float* W_slide = (const float*)d_in[3];
  const float* b_slide = (const float*)d_in[4];
  const float* W1      = (const float*)d_in[5];
  const float* b1      = (const float*)d_in[6];
  const float* W2      = (const float*)d_in[7];
  const float* b2      = (const float*)d_in[8];
  float* out = (float*)d_out;

  // workspace layout (halves). emb gets +4096 pad: padded windows read past
  // the logical end (finite poison * zero pad-weights, rows masked in pooling).
  _Float16* ws  = (_Float16*)d_ws;
  _Float16* emb = ws;                                   // 64*1024*304
  _Float16* Bf1 = emb + (size_t)MTOT * EMB_P + 4096;    // 512*1536
  _Float16* Bf2 = Bf1 + (size_t)H0 * K1P;               // 256*512
  _Float16* Bf3 = Bf2 + (size_t)H1D * H0;               // 128*256
  _Float16* h1  = Bf3 + (size_t)H2D * H1D;              // 65536*512
  _Float16* h2  = h1 + (size_t)MTOT * H0;               // 65536*256

  prep_kernel<<<GATHER_BLOCKS + WPREP_BLOCKS, 256, 0, stream>>>(
      x, table, emb, out, W_slide, W1, W2, Bf1, Bf2, Bf3);
  // L1: win @ W_slide + b_slide (no relu) -> h1 fp16
  gemm_nt<0><<<(MTOT / 128) * (H0 / 128), 256, 0, stream>>>(
      emb, Bf1, b_slide, h1, nullptr, nullptr, H0, K1P, EMB_P, H0 / 128);
  // L2: relu(h1 @ W1 + b1) -> h2 fp16
  gemm_nt<1><<<(MTOT / 128) * (H1D / 128), 256, 0, stream>>>(
      h1, Bf2, b1, h2, nullptr, nullptr, H1D, H0, H0, H1D / 128);
  // L3: relu(h2 @ W2 + b2), fused masked-mean pooling -> out
  gemm_nt<2><<<(MTOT / 128) * (H2D / 128), 256, 0, stream>>>(
      h2, Bf3, b2, nullptr, out, lengths, H2D, H1D, H1D, H2D / 128);
}

// Round 6
// 375.727 us; speedup vs baseline: 1.0819x; 1.0819x over previous
//
#include <hip/hip_runtime.h>

// Problem constants
#define B_N    64
#define S_LEN  1024
#define EMB    300
#define EMB_P  304              // padded token stride (halves) -> 608B, 16B-aligned
#define NGRAM  5
#define WPAD   1024             // windows per batch padded 1020 -> 1024
#define MTOT   (B_N * WPAD)     // 65536 rows
#define K1P    1536             // padded K for layer 1 (5*304 = 1520 -> 1536)
#define H0     512
#define H1D    256
#define H2D    128

#define GATHER_BLOCKS ((MTOT * (EMB_P / 4)) / 256)   // 19456
#define WPREP_THREADS (H0 * K1P + H1D * H0 + H2D * H1D)
#define WPREP_BLOCKS  ((WPREP_THREADS + 255) / 256)

typedef _Float16 half8 __attribute__((ext_vector_type(8)));
typedef float  floatx4 __attribute__((ext_vector_type(4)));

typedef const __attribute__((address_space(1))) void* gptr_t;
typedef __attribute__((address_space(3))) void* sptr_t;

__device__ __forceinline__ void gload16(const void* g, void* s) {
  __builtin_amdgcn_global_load_lds((gptr_t)g, (sptr_t)s, 16, 0, 0);
}

// ------------- fused prep: gather, zero out, weight layouts
// WsT: row-major K-major [n][k] over K'=1536 (GEMM1 stages it via LDS).
// Bf2/Bf3: FRAGMENT-major for the streaming GEMMs:
//   Bf[((n16*nK + ks)*64 + ((k>>3)&3)*16 + (n&15))*8 + (k&7)] = B^T[n][k]
__global__ void prep_kernel(const int* __restrict__ x,
                            const float* __restrict__ table,
                            _Float16* __restrict__ emb,
                            float* __restrict__ out,
                            const float* __restrict__ Ws,
                            const float* __restrict__ W1,
                            const float* __restrict__ W2,
                            _Float16* __restrict__ WsT,
                            _Float16* __restrict__ Bf2,
                            _Float16* __restrict__ Bf3) {
  const int bid = blockIdx.x;
  if (bid < GATHER_BLOCKS) {
    if (bid < 32) out[bid * 256 + threadIdx.x] = 0.0f;  // zero 8192 outputs
    const int CH = EMB_P / 4;  // 76
    int tid = bid * 256 + threadIdx.x;
    int tok = tid / CH;
    int c   = tid - tok * CH;
    int e   = c << 2;
    _Float16 h0, h1, h2, h3;
    if (e < EMB) {
      float4 v = *(const float4*)(table + (size_t)x[tok] * EMB + e);
      h0 = (_Float16)v.x; h1 = (_Float16)v.y; h2 = (_Float16)v.z; h3 = (_Float16)v.w;
    } else {
      h0 = h1 = h2 = h3 = (_Float16)0.0f;
    }
    union { float2 f2; _Float16 h[4]; } u;
    u.h[0] = h0; u.h[1] = h1; u.h[2] = h2; u.h[3] = h3;
    *(float2*)(emb + (size_t)tok * EMB_P + e) = u.f2;
  } else {
    int tid = (bid - GATHER_BLOCKS) * 256 + threadIdx.x;
    const int NS = H0 * K1P;
    const int N1 = H1D * H0;
    const int N2 = H2D * H1D;
    if (tid < NS) {                 // layer1 weights, row-major [n][k]
      int n = tid / K1P, k = tid - n * K1P;
      float v = 0.0f;
      if (k < NGRAM * EMB_P) {
        int tn = k / EMB_P, e = k - tn * EMB_P;
        if (e < EMB) v = Ws[(size_t)(tn * EMB + e) * H0 + n];
      }
      WsT[tid] = (_Float16)v;
    } else if (tid < NS + N1) {     // layer2: n in [256), k in [512), nK=16
      int t = tid - NS;
      int n = t / H0, k = t - n * H0;
      float v = W1[(size_t)k * H1D + n];
      int idx = ((((n >> 4) * 16 + (k >> 5)) << 6) + (((k >> 3) & 3) << 4) + (n & 15)) * 8 + (k & 7);
      Bf2[idx] = (_Float16)v;
    } else if (tid < NS + N1 + N2) {  // layer3: n in [128), k in [256), nK=8
      int t = tid - (NS + N1);
      int n = t / H1D, k = t - n * H1D;
      float v = W2[(size_t)k * H2D + n];
      int idx = ((((n >> 4) * 8 + (k >> 5)) << 6) + (((k >> 3) & 3) << 4) + (n & 15)) * 8 + (k & 7);
      Bf3[idx] = (_Float16)v;
    }
  }
}

// --------------------------------------------- GEMM1: LDS-staged NT GEMM
// C = A[M,K] @ WsT[N,K]^T, 128x128 tile, BK=32, dbuf LDS, 1 barrier/step,
// XOR-swizzled chunks (0 conflicts), XCD-affine swizzle (round-3 structure).
// Epilogue: +bias (no relu), store h1 in A-FRAGMENT-major for GEMM2.
__global__ __launch_bounds__(256, 4)
void gemm1_lds(const _Float16* __restrict__ A, const _Float16* __restrict__ Bt,
               const float* __restrict__ bias, _Float16* __restrict__ Cf,
               int N, int K, int lda, int nTiles, int nKout) {
  __shared__ _Float16 sA[2][128 * 32];
  __shared__ _Float16 sB[2][128 * 32];

  const int tid  = threadIdx.x;
  const int wave = tid >> 6;
  const int lane = tid & 63;
  const int wr   = wave >> 1, wc = wave & 1;
  const int quad = lane >> 4, l16 = lane & 15;

  const int perX = gridDim.x >> 3;
  const int L    = (blockIdx.x & 7) * perX + (blockIdx.x >> 3);
  const int mt = L / nTiles;
  const int nt = L - mt * nTiles;
  const long mBase = (long)mt << 7;
  const int  nBase = nt << 7;

  const int sRow   = (wave << 4) + (lane >> 2);        // 0..63
  const int sCol   = (lane & 3) << 3;                  // LDS slot (halves)
  const int gCol   = ((lane & 3) ^ ((sRow >> 1) & 3)) << 3;  // global chunk

  const _Float16* aG0 = A + (mBase + sRow) * lda + gCol;
  const _Float16* aG1 = A + (mBase + sRow + 64) * lda + gCol;
  const _Float16* bG0 = Bt + (long)(nBase + sRow) * K + gCol;
  const _Float16* bG1 = Bt + (long)(nBase + sRow + 64) * K + gCol;
  const int offS0 = sRow * 32 + sCol;
  const int offS1 = offS0 + 64 * 32;

  const int fswz = ((l16 >> 1) & 3) << 3;

  floatx4 acc[4][4] = {};

  const int nK = K >> 5;
  gload16(aG0, &sA[0][offS0]);
  gload16(aG1, &sA[0][offS1]);
  gload16(bG0, &sB[0][offS0]);
  gload16(bG1, &sB[0][offS1]);

  for (int kk = 0; kk < nK; kk++) {
    const int cur = kk & 1;
    __syncthreads();
    if (kk + 1 < nK) {
      const int ko = (kk + 1) << 5;
      gload16(aG0 + ko, &sA[cur ^ 1][offS0]);
      gload16(aG1 + ko, &sA[cur ^ 1][offS1]);
      gload16(bG0 + ko, &sB[cur ^ 1][offS0]);
      gload16(bG1 + ko, &sB[cur ^ 1][offS1]);
    }
    half8 aF[4], bF[4];
#pragma unroll
    for (int i = 0; i < 4; i++)
      aF[i] = *(const half8*)(&sA[cur][((wr << 6) + (i << 4) + l16) * 32 + ((quad << 3) ^ fswz)]);
#pragma unroll
    for (int j = 0; j < 4; j++)
      bF[j] = *(const half8*)(&sB[cur][((wc << 6) + (j << 4) + l16) * 32 + ((quad << 3) ^ fswz)]);
#pragma unroll
    for (int i = 0; i < 4; i++)
#pragma unroll
      for (int j = 0; j < 4; j++)
        acc[i][j] = __builtin_amdgcn_mfma_f32_16x16x32_f16(aF[i], bF[j], acc[i][j], 0, 0, 0);
  }

  // epilogue: frag-major store.  value at (row,col):
  //   Cf[(( (row>>4)*nKout + col>>5 )*64 + ((col>>3)&3)*16 + (row&15))*8 + (col&7)]
#pragma unroll
  for (int j = 0; j < 4; j++) {
    int col = nBase + (wc << 6) + (j << 4) + l16;
    float bv = bias[col];
    const size_t cbase = ((size_t)(col >> 5) << 9) + (((col >> 3) & 3) << 7) + (col & 7);
#pragma unroll
    for (int i = 0; i < 4; i++) {
      int m16 = (mt << 3) + (wr << 2) + i;
      size_t base = (((size_t)m16 * nKout) << 9) + cbase + ((quad << 2) << 3);
#pragma unroll
      for (int r = 0; r < 4; r++)
        Cf[base + (r << 3)] = (_Float16)(acc[i][j][r] + bv);
    }
  }
}

// ------------------------------- streaming GEMM (no LDS, no barriers)
// A and B both FRAGMENT-major: every load is a coalesced 1KB dwordx4.
// EPI 1: +bias, relu, store C frag-major (feeds next stream GEMM).
// EPI 2: +bias, relu, fused ragged-mean pooling (N=128, one N-tile).
template <int EPI>
__global__ __launch_bounds__(256, 4)
void gemm_stream(const _Float16* __restrict__ Af, const _Float16* __restrict__ Bf,
                 const float* __restrict__ bias, _Float16* __restrict__ Cf,
                 float* __restrict__ out, const int* __restrict__ lengths,
                 int nKa, int nTiles, int nKout) {
  const int tid  = threadIdx.x;
  const int wave = tid >> 6;
  const int lane = tid & 63;
  const int wr   = wave >> 1, wc = wave & 1;
  const int quad = lane >> 4, l16 = lane & 15;

  const int perX = gridDim.x >> 3;
  const int L    = (blockIdx.x & 7) * perX + (blockIdx.x >> 3);
  const int mt = L / nTiles;
  const int nt = L - mt * nTiles;
  const int nBase = nt << 7;

  const _Float16* aR[4];
#pragma unroll
  for (int i = 0; i < 4; i++)
    aR[i] = Af + (((size_t)((mt << 3) + (wr << 2) + i) * nKa) << 9) + (lane << 3);
  const _Float16* bR[4];
#pragma unroll
  for (int j = 0; j < 4; j++)
    bR[j] = Bf + (((size_t)((nBase >> 4) + (wc << 2) + j) * nKa) << 9) + (lane << 3);

  floatx4 acc[4][4] = {};

#pragma unroll 2
  for (int kk = 0; kk < nKa; kk++) {
    const size_t ko = (size_t)kk << 9;
    half8 aF[4], bF[4];
#pragma unroll
    for (int i = 0; i < 4; i++) aF[i] = *(const half8*)(aR[i] + ko);
#pragma unroll
    for (int j = 0; j < 4; j++) bF[j] = *(const half8*)(bR[j] + ko);
#pragma unroll
    for (int i = 0; i < 4; i++)
#pragma unroll
      for (int j = 0; j < 4; j++)
        acc[i][j] = __builtin_amdgcn_mfma_f32_16x16x32_f16(aF[i], bF[j], acc[i][j], 0, 0, 0);
  }

  if constexpr (EPI == 1) {
#pragma unroll
    for (int j = 0; j < 4; j++) {
      int col = nBase + (wc << 6) + (j << 4) + l16;
      float bv = bias[col];
      const size_t cbase = ((size_t)(col >> 5) << 9) + (((col >> 3) & 3) << 7) + (col & 7);
#pragma unroll
      for (int i = 0; i < 4; i++) {
        int m16 = (mt << 3) + (wr << 2) + i;
        size_t base = (((size_t)m16 * nKout) << 9) + cbase + ((quad << 2) << 3);
#pragma unroll
        for (int r = 0; r < 4; r++)
          Cf[base + (r << 3)] = (_Float16)fmaxf(acc[i][j][r] + bv, 0.0f);
      }
    }
  } else {
    // fused relu + ragged-mean pooling; block covers one batch (mt>>3).
    __shared__ float red[2][128];
    int b = mt >> 3;
    int validw = lengths[b] - (NGRAM - 1);
    float inv = 1.0f / (float)validw;
    int wBase = ((mt & 7) << 7) + (wr << 6);
#pragma unroll
    for (int j = 0; j < 4; j++) {
      int col = (wc << 6) + (j << 4) + l16;
      float bv = bias[col];
      float p = 0.0f;
#pragma unroll
      for (int i = 0; i < 4; i++) {
#pragma unroll
        for (int r = 0; r < 4; r++) {
          int w = wBase + (i << 4) + (quad << 2) + r;
          float v = fmaxf(acc[i][j][r] + bv, 0.0f);
          p += (w < validw) ? v : 0.0f;
        }
      }
      p *= inv;
      p += __shfl_xor(p, 16, 64);
      p += __shfl_xor(p, 32, 64);
      if (quad == 0) red[wr][col] = p;
    }
    __syncthreads();
    if (tid < 128) atomicAdd(out + b * H2D + tid, red[0][tid] + red[1][tid]);
  }
}

// ---------------------------------------------------------------- launcher
extern "C" void kernel_launch(void* const* d_in, const int* in_sizes, int n_in,
                              void* d_out, int out_size, void* d_ws, size_t ws_size,
                              hipStream_t stream) {
  const int*   x       = (const int*)d_in[0];
  const int*   lengths = (const int*)d_in[1];
  const float* table   = (const float*)d_in[2];
  const float* W_slide = (const float*)d_in[3];
  const float* b_slide = (const float*)d_in[4];
  const float* W1      = (const float*)d_in[5];
  const float* b1      = (const float*)d_in[6];
  const float* W2      = (const float*)d_in[7];
  const float* b2      = (const float*)d_in[8];
  float* out = (float*)d_out;

  // workspace layout (halves). emb gets +4096 pad: padded windows read past
  // the logical end (finite poison * zero pad-weights, rows masked in pooling).
  _Float16* ws  = (_Float16*)d_ws;
  _Float16* emb = ws;                                   // 64*1024*304
  _Float16* WsT = emb + (size_t)MTOT * EMB_P + 4096;    // 512*1536
  _Float16* Bf2 = WsT + (size_t)H0 * K1P;               // 256*512
  _Float16* Bf3 = Bf2 + (size_t)H1D * H0;               // 128*256
  _Float16* h1f = Bf3 + (size_t)H2D * H1D;              // 65536*512 (frag-major)
  _Float16* h2f = h1f + (size_t)MTOT * H0;              // 65536*256 (frag-major)

  prep_kernel<<<GATHER_BLOCKS + WPREP_BLOCKS, 256, 0, stream>>>(
      x, table, emb, out, W_slide, W1, W2, WsT, Bf2, Bf3);
  // L1: win @ W_slide + b_slide (no relu) -> h1f (frag-major), LDS GEMM
  gemm1_lds<<<(MTOT / 128) * (H0 / 128), 256, 0, stream>>>(
      emb, WsT, b_slide, h1f, H0, K1P, EMB_P, H0 / 128, H0 / 32);
  // L2: relu(h1 @ W1 + b1) -> h2f (frag-major), streaming GEMM
  gemm_stream<1><<<(MTOT / 128) * (H1D / 128), 256, 0, stream>>>(
      h1f, Bf2, b1, h2f, nullptr, nullptr, H0 / 32, H1D / 128, H1D / 32);
  // L3: relu(h2 @ W2 + b2), fused masked-mean pooling -> out
  gemm_stream<2><<<(MTOT / 128) * (H2D / 128), 256, 0, stream>>>(
      h2f, Bf3, b2, nullptr, out, lengths, H1D / 32, H2D / 128, 0);
}

// Round 7
// 329.216 us; speedup vs baseline: 1.2348x; 1.1413x over previous
//
#include <hip/hip_runtime.h>

// Problem constants
#define B_N    64
#define S_LEN  1024
#define EMB    300
#define EMB_P  304              // padded token stride (halves) -> 608B, 16B-aligned
#define NGRAM  5
#define WPAD   1024
#define MTOT   (B_N * WPAD)     // 65536 rows
#define K1P    1536             // padded K for layer 1 (5*304 = 1520 -> 1536)
#define H0     512
#define H1D    256
#define H2D    128
#define NK1    (K1P / 32)       // 48 B-frag chunks for layer 1
#define NSTEP1 (K1P / 64)       // 24 K-loop steps (BK=64)

#define GATHER_BLOCKS ((MTOT * (EMB_P / 4)) / 256)   // 19456
#define WPREP_THREADS (H0 * K1P + H1D * H0 + H2D * H1D)
#define WPREP_BLOCKS  ((WPREP_THREADS + 255) / 256)

typedef _Float16 half8 __attribute__((ext_vector_type(8)));
typedef float  floatx4 __attribute__((ext_vector_type(4)));

typedef const __attribute__((address_space(1))) void* gptr_t;
typedef __attribute__((address_space(3))) void* sptr_t;

__device__ __forceinline__ void gload16(const void* g, void* s) {
  __builtin_amdgcn_global_load_lds((gptr_t)g, (sptr_t)s, 16, 0, 0);
}

// ---- fused prep: gather table[x]->fp16, zero out, weights -> frag-major
// Frag-major: Bf[((n16*nK + k>>5)*64 + ((k>>3)&3)*16 + (n&15))*8 + (k&7)]
// Weight reads are coalesced (consecutive threads -> consecutive n).
__global__ void prep_kernel(const int* __restrict__ x,
                            const float* __restrict__ table,
                            _Float16* __restrict__ emb,
                            float* __restrict__ out,
                            const float* __restrict__ Ws,
                            const float* __restrict__ W1,
                            const float* __restrict__ W2,
                            _Float16* __restrict__ Bf1,
                            _Float16* __restrict__ Bf2,
                            _Float16* __restrict__ Bf3) {
  const int bid = blockIdx.x;
  if (bid < GATHER_BLOCKS) {
    if (bid < 32) out[bid * 256 + threadIdx.x] = 0.0f;  // zero 8192 outputs
    const int CH = EMB_P / 4;  // 76
    int tid = bid * 256 + threadIdx.x;
    int tok = tid / CH;
    int c   = tid - tok * CH;
    int e   = c << 2;
    _Float16 h0, h1, h2, h3;
    if (e < EMB) {
      float4 v = *(const float4*)(table + (size_t)x[tok] * EMB + e);
      h0 = (_Float16)v.x; h1 = (_Float16)v.y; h2 = (_Float16)v.z; h3 = (_Float16)v.w;
    } else {
      h0 = h1 = h2 = h3 = (_Float16)0.0f;
    }
    union { float2 f2; _Float16 h[4]; } u;
    u.h[0] = h0; u.h[1] = h1; u.h[2] = h2; u.h[3] = h3;
    *(float2*)(emb + (size_t)tok * EMB_P + e) = u.f2;
  } else {
    int tid = (bid - GATHER_BLOCKS) * 256 + threadIdx.x;
    const int NS = H0 * K1P;
    const int N1 = H1D * H0;
    const int N2 = H2D * H1D;
    if (tid < NS) {                       // layer1: coalesced over n
      int n = tid & 511, k = tid >> 9;    // k < 1536
      float v = 0.0f;
      if (k < NGRAM * EMB_P) {
        int tn = k / EMB_P, e = k - tn * EMB_P;
        if (e < EMB) v = Ws[(size_t)(tn * EMB + e) * H0 + n];
      }
      int idx = ((((n >> 4) * NK1 + (k >> 5)) << 6) + (((k >> 3) & 3) << 4) + (n & 15)) * 8 + (k & 7);
      Bf1[idx] = (_Float16)v;
    } else if (tid < NS + N1) {           // layer2: nK=16
      int t = tid - NS;
      int n = t & 255, k = t >> 8;        // k < 512
      float v = W1[(size_t)k * H1D + n];
      int idx = ((((n >> 4) * 16 + (k >> 5)) << 6) + (((k >> 3) & 3) << 4) + (n & 15)) * 8 + (k & 7);
      Bf2[idx] = (_Float16)v;
    } else if (tid < NS + N1 + N2) {      // layer3: nK=8
      int t = tid - (NS + N1);
      int n = t & 127, k = t >> 7;        // k < 256
      float v = W2[(size_t)k * H2D + n];
      int idx = ((((n >> 4) * 8 + (k >> 5)) << 6) + (((k >> 3) & 3) << 4) + (n & 15)) * 8 + (k & 7);
      Bf3[idx] = (_Float16)v;
    }
  }
}

// ------------------------- GEMM1: A LDS-staged (BK=64), B streamed from
// frag-major global (coalesced 1KB loads). dbuf LDS + 1 barrier/step,
// XOR-swizzle on A chunks (slot = chunk ^ (row&7), 2-way max = free).
// Epilogue: acc -> LDS -> coalesced dwordx4 frag-major h1f stores.
__global__ __launch_bounds__(256, 3)
void gemm1(const _Float16* __restrict__ A, const _Float16* __restrict__ Bf,
           const float* __restrict__ bias, _Float16* __restrict__ Cf) {
  __shared__ _Float16 sA[2][128 * 64];   // 2 x 16 KB

  const int tid  = threadIdx.x;
  const int wave = tid >> 6, lane = tid & 63;
  const int wr   = wave >> 1, wc = wave & 1;
  const int quad = lane >> 4, l16 = lane & 15;

  const int perX = gridDim.x >> 3;
  const int L  = (blockIdx.x & 7) * perX + (blockIdx.x >> 3);
  const int mt = L >> 2, nt = L & 3;     // nTiles = 4
  const long mBase = (long)mt << 7;
  const int  nBase = nt << 7;

  // staging: round p stages rows p*32..p*32+31; lane -> (row, slot=lane&7);
  // fetches global chunk c = slot ^ (row&7). LDS dst = uniform + lane*16B.
  const int srow0  = (wave << 3) + (lane >> 3);  // 0..31
  const int schunk = lane & 7;
  const _Float16* aG[4];
  int sOff[4];
#pragma unroll
  for (int p = 0; p < 4; p++) {
    int row = (p << 5) + srow0;
    int c   = schunk ^ (row & 7);
    aG[p]   = A + (mBase + row) * EMB_P + (c << 3);
    sOff[p] = (row << 6) + (schunk << 3);        // == wave-uniform + lane*8
  }

  const _Float16* bG[4];
#pragma unroll
  for (int j = 0; j < 4; j++)
    bG[j] = Bf + (((size_t)((nBase >> 4) + (wc << 2) + j) * NK1) << 9) + (lane << 3);

  // A-frag LDS offsets (constant over kk): row r, wanted chunk s*4+quad
  int aOff[2][4];
#pragma unroll
  for (int s = 0; s < 2; s++)
#pragma unroll
    for (int i = 0; i < 4; i++) {
      int r    = (wr << 6) + (i << 4) + l16;
      int slot = ((s << 2) + quad) ^ (l16 & 7);
      aOff[s][i] = (r << 6) + (slot << 3);
    }

  floatx4 acc[4][4] = {};

#pragma unroll
  for (int p = 0; p < 4; p++) gload16(aG[p], &sA[0][sOff[p]]);

  for (int kk = 0; kk < NSTEP1; kk++) {
    const int cur = kk & 1;
    __syncthreads();
    if (kk + 1 < NSTEP1) {
      const int ko = (kk + 1) << 6;
#pragma unroll
      for (int p = 0; p < 4; p++) gload16(aG[p] + ko, &sA[cur ^ 1][sOff[p]]);
    }
    half8 bFr[2][4];
#pragma unroll
    for (int s = 0; s < 2; s++)
#pragma unroll
      for (int j = 0; j < 4; j++)
        bFr[s][j] = *(const half8*)(bG[j] + (size_t)(((kk << 1) + s) << 9));
#pragma unroll
    for (int s = 0; s < 2; s++) {
      half8 aFr[4];
#pragma unroll
      for (int i = 0; i < 4; i++)
        aFr[i] = *(const half8*)(&sA[cur][aOff[s][i]]);
#pragma unroll
      for (int i = 0; i < 4; i++)
#pragma unroll
        for (int j = 0; j < 4; j++)
          acc[i][j] = __builtin_amdgcn_mfma_f32_16x16x32_f16(aFr[i], bFr[s][j], acc[i][j], 0, 0, 0);
    }
  }

  // ---- epilogue: acc -> LDS (frag-major local) -> coalesced dwordx4 stores
  __syncthreads();
  _Float16* cs = &sA[0][0];  // 16384 halves = 32 KB, exactly one C-tile fp16
#pragma unroll
  for (int j = 0; j < 4; j++) {
    int cl = (wc << 6) + (j << 4) + l16;   // local col 0..127
    float bv = bias[nBase + cl];
    int ksl = cl >> 5;
    int sub_hi = ((cl >> 3) & 3) << 4;
    int c7 = cl & 7;
#pragma unroll
    for (int i = 0; i < 4; i++) {
      int m16l = (wr << 2) + i;
#pragma unroll
      for (int r = 0; r < 4; r++) {
        int ml = (quad << 2) + r;          // m & 15
        cs[(((m16l << 2) + ksl) << 9) + ((sub_hi + ml) << 3) + c7] =
            (_Float16)(acc[i][j][r] + bv);
      }
    }
  }
  __syncthreads();
#pragma unroll
  for (int it = 0; it < 8; it++) {
    int cid = (it << 2) + wave;            // 0..31: chunk = (m16l, ksl)
    int m16l = cid >> 2, ksl = cid & 3;
    size_t g = ((size_t)(((mt << 3) + m16l) * 16 + (nt << 2) + ksl) << 9) + (lane << 3);
    *(half8*)(Cf + g) = *(const half8*)(cs + (cid << 9) + (lane << 3));
  }
}

// ------------------- fused GEMM2+GEMM3: h2 never leaves the CU.
// Phase A (G2): 128x256 tile, 4 waves (2x2, 64x128 each), streaming
// frag-major A (h1f) and B (Bf2) — all coalesced, no barriers.
// h2 (+bias1, relu) -> LDS frag-major (64 KB). Phase B (G3): 128x128 from
// LDS-A + Bf3, then fused relu + ragged-mean pooling via atomics.
__global__ __launch_bounds__(256, 2)
void gemm23(const _Float16* __restrict__ Af, const _Float16* __restrict__ B2,
            const _Float16* __restrict__ B3, const float* __restrict__ bias1,
            const float* __restrict__ bias2, float* __restrict__ out,
            const int* __restrict__ lengths) {
  __shared__ _Float16 sH[32768];   // 64 KB: [m16l(8)][ks(8)][sub(64)][8]
  __shared__ float red[2][128];

  const int tid  = threadIdx.x;
  const int wave = tid >> 6, lane = tid & 63;
  const int wr   = wave >> 1, wc = wave & 1;
  const int quad = lane >> 4, l16 = lane & 15;
  const int mt = blockIdx.x;

  const _Float16* aR[4];
#pragma unroll
  for (int i = 0; i < 4; i++)
    aR[i] = Af + (((size_t)((mt << 3) + (wr << 2) + i) * 16) << 9) + (lane << 3);
  const _Float16* bR[8];
#pragma unroll
  for (int j = 0; j < 8; j++)
    bR[j] = B2 + (((size_t)((wc << 3) + j) * 16) << 9) + (lane << 3);

  floatx4 acc2[4][8] = {};
#pragma unroll 2
  for (int kk = 0; kk < 16; kk++) {
    const size_t ko = (size_t)kk << 9;
    half8 aF[4], bF[8];
#pragma unroll
    for (int i = 0; i < 4; i++) aF[i] = *(const half8*)(aR[i] + ko);
#pragma unroll
    for (int j = 0; j < 8; j++) bF[j] = *(const half8*)(bR[j] + ko);
#pragma unroll
    for (int i = 0; i < 4; i++)
#pragma unroll
      for (int j = 0; j < 8; j++)
        acc2[i][j] = __builtin_amdgcn_mfma_f32_16x16x32_f16(aF[i], bF[j], acc2[i][j], 0, 0, 0);
  }

  // h2 tile -> LDS frag-major, +bias1, relu
#pragma unroll
  for (int j = 0; j < 8; j++) {
    int n = (wc << 7) + (j << 4) + l16;    // h2 col 0..255
    float bv = bias1[n];
    int ks = n >> 5;
    int sub_hi = ((n >> 3) & 3) << 4;
    int c7 = n & 7;
#pragma unroll
    for (int i = 0; i < 4; i++) {
      int m16l = (wr << 2) + i;
#pragma unroll
      for (int r = 0; r < 4; r++) {
        int ml = (quad << 2) + r;
        sH[(((m16l << 3) + ks) << 9) + ((sub_hi + ml) << 3) + c7] =
            (_Float16)fmaxf(acc2[i][j][r] + bv, 0.0f);
      }
    }
  }
  __syncthreads();

  // Phase B: G3 (K=256 from LDS)
  const _Float16* b3R[4];
#pragma unroll
  for (int j = 0; j < 4; j++)
    b3R[j] = B3 + (((size_t)((wc << 2) + j) * 8) << 9) + (lane << 3);

  floatx4 acc3[4][4] = {};
#pragma unroll
  for (int ks = 0; ks < 8; ks++) {
    half8 aF[4], bF[4];
#pragma unroll
    for (int i = 0; i < 4; i++)
      aF[i] = *(const half8*)(sH + (((((wr << 2) + i) << 3) + ks) << 9) + (lane << 3));
#pragma unroll
    for (int j = 0; j < 4; j++) bF[j] = *(const half8*)(b3R[j] + ((size_t)ks << 9));
#pragma unroll
    for (int i = 0; i < 4; i++)
#pragma unroll
      for (int j = 0; j < 4; j++)
        acc3[i][j] = __builtin_amdgcn_mfma_f32_16x16x32_f16(aF[i], bF[j], acc3[i][j], 0, 0, 0);
  }

  // fused relu + ragged-mean pooling (C/D: col=lane&15, row=quad*4+r)
  int b = mt >> 3;
  int validw = lengths[b] - (NGRAM - 1);
  float inv = 1.0f / (float)validw;
  int wBase = ((mt & 7) << 7) + (wr << 6);
#pragma unroll
  for (int j = 0; j < 4; j++) {
    int col = (wc << 6) + (j << 4) + l16;
    float bv = bias2[col];
    float p = 0.0f;
#pragma unroll
    for (int i = 0; i < 4; i++) {
#pragma unroll
      for (int r = 0; r < 4; r++) {
        int w = wBase + (i << 4) + (quad << 2) + r;
        float v = fmaxf(acc3[i][j][r] + bv, 0.0f);
        p += (w < validw) ? v : 0.0f;
      }
    }
    p *= inv;
    p += __shfl_xor(p, 16, 64);
    p += __shfl_xor(p, 32, 64);
    if (quad == 0) red[wr][col] = p;
  }
  __syncthreads();
  if (tid < 128) atomicAdd(out + b * H2D + tid, red[0][tid] + red[1][tid]);
}

// ---------------------------------------------------------------- launcher
extern "C" void kernel_launch(void* const* d_in, const int* in_sizes, int n_in,
                              void* d_out, int out_size, void* d_ws, size_t ws_size,
                              hipStream_t stream) {
  const int*   x       = (const int*)d_in[0];
  const int*   lengths = (const int*)d_in[1];
  const float* table   = (const float*)d_in[2];
  const float* W_slide = (const float*)d_in[3];
  const float* b_slide = (const float*)d_in[4];
  const float* W1      = (const float*)d_in[5];
  const float* b1      = (const float*)d_in[6];
  const float* W2      = (const float*)d_in[7];
  const float* b2      = (const float*)d_in[8];
  float* out = (float*)d_out;

  // workspace (halves). emb +4096 pad: tail windows read past logical end
  // (finite poison * masked rows, see pooling mask).
  _Float16* ws  = (_Float16*)d_ws;
  _Float16* emb = ws;                                   // 64*1024*304
  _Float16* Bf1 = emb + (size_t)MTOT * EMB_P + 4096;    // 512*1536 frag-major
  _Float16* Bf2 = Bf1 + (size_t)H0 * K1P;               // 256*512  frag-major
  _Float16* Bf3 = Bf2 + (size_t)H1D * H0;               // 128*256  frag-major
  _Float16* h1f = Bf3 + (size_t)H2D * H1D;              // 65536*512 frag-major

  prep_kernel<<<GATHER_BLOCKS + WPREP_BLOCKS, 256, 0, stream>>>(
      x, table, emb, out, W_slide, W1, W2, Bf1, Bf2, Bf3);
  // L1: win @ W_slide + b_slide -> h1f (frag-major)
  gemm1<<<(MTOT / 128) * (H0 / 128), 256, 0, stream>>>(emb, Bf1, b_slide, h1f);
  // L2+L3 fused: relu(h1@W1+b1) -> LDS -> relu(.@W2+b2) -> masked-mean pool
  gemm23<<<MTOT / 128, 256, 0, stream>>>(h1f, Bf2, Bf3, b1, b2, out, lengths);
}

// Round 8
// 327.761 us; speedup vs baseline: 1.2402x; 1.0044x over previous
//
#include <hip/hip_runtime.h>

// Problem constants
#define B_N    64
#define S_LEN  1024
#define EMB    300
#define EMB_P  304              // padded token stride (halves) -> 608B, 16B-aligned
#define NGRAM  5
#define WPAD   1024
#define MTOT   (B_N * WPAD)     // 65536 rows
#define K1P    1536             // padded K for layer 1 (5*304 = 1520 -> 1536)
#define H0     512
#define H1D    256
#define H2D    128
#define NK1    (K1P / 32)       // 48 B-frag chunks for layer 1
#define NSTEP1 (K1P / 64)       // 24 K-loop steps (BK=64)

#define GATHER_BLOCKS ((MTOT * (EMB_P / 4)) / 256)   // 19456
#define WPREP_THREADS (H0 * K1P + H1D * H0 + H2D * H1D)
#define WPREP_BLOCKS  ((WPREP_THREADS + 255) / 256)

typedef _Float16 half8 __attribute__((ext_vector_type(8)));
typedef float  floatx4 __attribute__((ext_vector_type(4)));

typedef const __attribute__((address_space(1))) void* gptr_t;
typedef __attribute__((address_space(3))) void* sptr_t;

__device__ __forceinline__ void gload16(const void* g, void* s) {
  __builtin_amdgcn_global_load_lds((gptr_t)g, (sptr_t)s, 16, 0, 0);
}

// ---- fused prep: gather table[x]->fp16, zero out, weights -> frag-major
// Frag-major: Bf[((n16*nK + k>>5)*64 + ((k>>3)&3)*16 + (n&15))*8 + (k&7)]
__global__ void prep_kernel(const int* __restrict__ x,
                            const float* __restrict__ table,
                            _Float16* __restrict__ emb,
                            float* __restrict__ out,
                            const float* __restrict__ Ws,
                            const float* __restrict__ W1,
                            const float* __restrict__ W2,
                            _Float16* __restrict__ Bf1,
                            _Float16* __restrict__ Bf2,
                            _Float16* __restrict__ Bf3) {
  const int bid = blockIdx.x;
  if (bid < GATHER_BLOCKS) {
    if (bid < 32) out[bid * 256 + threadIdx.x] = 0.0f;  // zero 8192 outputs
    const int CH = EMB_P / 4;  // 76
    int tid = bid * 256 + threadIdx.x;
    int tok = tid / CH;
    int c   = tid - tok * CH;
    int e   = c << 2;
    _Float16 h0, h1, h2, h3;
    if (e < EMB) {
      float4 v = *(const float4*)(table + (size_t)x[tok] * EMB + e);
      h0 = (_Float16)v.x; h1 = (_Float16)v.y; h2 = (_Float16)v.z; h3 = (_Float16)v.w;
    } else {
      h0 = h1 = h2 = h3 = (_Float16)0.0f;
    }
    union { float2 f2; _Float16 h[4]; } u;
    u.h[0] = h0; u.h[1] = h1; u.h[2] = h2; u.h[3] = h3;
    *(float2*)(emb + (size_t)tok * EMB_P + e) = u.f2;
  } else {
    int tid = (bid - GATHER_BLOCKS) * 256 + threadIdx.x;
    const int NS = H0 * K1P;
    const int N1 = H1D * H0;
    const int N2 = H2D * H1D;
    if (tid < NS) {                       // layer1: coalesced over n
      int n = tid & 511, k = tid >> 9;    // k < 1536
      float v = 0.0f;
      if (k < NGRAM * EMB_P) {
        int tn = k / EMB_P, e = k - tn * EMB_P;
        if (e < EMB) v = Ws[(size_t)(tn * EMB + e) * H0 + n];
      }
      int idx = ((((n >> 4) * NK1 + (k >> 5)) << 6) + (((k >> 3) & 3) << 4) + (n & 15)) * 8 + (k & 7);
      Bf1[idx] = (_Float16)v;
    } else if (tid < NS + N1) {           // layer2: nK=16
      int t = tid - NS;
      int n = t & 255, k = t >> 8;        // k < 512
      float v = W1[(size_t)k * H1D + n];
      int idx = ((((n >> 4) * 16 + (k >> 5)) << 6) + (((k >> 3) & 3) << 4) + (n & 15)) * 8 + (k & 7);
      Bf2[idx] = (_Float16)v;
    } else if (tid < NS + N1 + N2) {      // layer3: nK=8
      int t = tid - (NS + N1);
      int n = t & 127, k = t >> 7;        // k < 256
      float v = W2[(size_t)k * H2D + n];
      int idx = ((((n >> 4) * 8 + (k >> 5)) << 6) + (((k >> 3) & 3) << 4) + (n & 15)) * 8 + (k & 7);
      Bf3[idx] = (_Float16)v;
    }
  }
}

// ------------------------- GEMM1: A LDS-staged (BK=64), B streamed from
// frag-major global (coalesced 1KB loads) with REGISTER double-buffering:
// step k+1's B-frags are prefetched during step k's MFMA phase, so the
// L2 latency is covered (B-L2 BW is the binding pipe at ~60 B/cyc/CU).
// dbuf LDS + 1 barrier/step, XOR-swizzled A chunks (conflict-free).
// Epilogue: acc -> LDS -> coalesced dwordx4 frag-major h1f stores.
__global__ __launch_bounds__(256, 3)
void gemm1(const _Float16* __restrict__ A, const _Float16* __restrict__ Bf,
           const float* __restrict__ bias, _Float16* __restrict__ Cf) {
  __shared__ _Float16 sA[2][128 * 64];   // 2 x 16 KB

  const int tid  = threadIdx.x;
  const int wave = tid >> 6, lane = tid & 63;
  const int wr   = wave >> 1, wc = wave & 1;
  const int quad = lane >> 4, l16 = lane & 15;

  const int perX = gridDim.x >> 3;
  const int L  = (blockIdx.x & 7) * perX + (blockIdx.x >> 3);
  const int mt = L >> 2, nt = L & 3;     // nTiles = 4
  const long mBase = (long)mt << 7;
  const int  nBase = nt << 7;

  // staging: round p stages rows p*32..p*32+31; lane -> (row, slot=lane&7);
  // fetches global chunk c = slot ^ (row&7). LDS dst = uniform + lane*16B.
  const int srow0  = (wave << 3) + (lane >> 3);  // 0..31
  const int schunk = lane & 7;
  const _Float16* aG[4];
  int sOff[4];
#pragma unroll
  for (int p = 0; p < 4; p++) {
    int row = (p << 5) + srow0;
    int c   = schunk ^ (row & 7);
    aG[p]   = A + (mBase + row) * EMB_P + (c << 3);
    sOff[p] = (row << 6) + (schunk << 3);
  }

  const _Float16* bG[4];
#pragma unroll
  for (int j = 0; j < 4; j++)
    bG[j] = Bf + (((size_t)((nBase >> 4) + (wc << 2) + j) * NK1) << 9) + (lane << 3);

  // A-frag LDS offsets (constant over kk): row r, wanted chunk s*4+quad
  int aOff[2][4];
#pragma unroll
  for (int s = 0; s < 2; s++)
#pragma unroll
    for (int i = 0; i < 4; i++) {
      int r    = (wr << 6) + (i << 4) + l16;
      int slot = ((s << 2) + quad) ^ (l16 & 7);
      aOff[s][i] = (r << 6) + (slot << 3);
    }

  floatx4 acc[4][4] = {};

  // prologue: A step 0 -> LDS buf0; B step 0 -> registers
#pragma unroll
  for (int p = 0; p < 4; p++) gload16(aG[p], &sA[0][sOff[p]]);
  half8 bCur[2][4], bNxt[2][4];
#pragma unroll
  for (int s = 0; s < 2; s++)
#pragma unroll
    for (int j = 0; j < 4; j++)
      bCur[s][j] = *(const half8*)(bG[j] + ((size_t)s << 9));

#pragma unroll 2
  for (int kk = 0; kk < NSTEP1; kk++) {
    const int cur = kk & 1;
    __syncthreads();
    if (kk + 1 < NSTEP1) {
      const int ko = (kk + 1) << 6;
#pragma unroll
      for (int p = 0; p < 4; p++) gload16(aG[p] + ko, &sA[cur ^ 1][sOff[p]]);
      // prefetch next step's B-frags: in flight across the whole MFMA phase
#pragma unroll
      for (int s = 0; s < 2; s++)
#pragma unroll
        for (int j = 0; j < 4; j++)
          bNxt[s][j] = *(const half8*)(bG[j] + (size_t)((((kk + 1) << 1) + s) << 9));
    }
#pragma unroll
    for (int s = 0; s < 2; s++) {
      half8 aFr[4];
#pragma unroll
      for (int i = 0; i < 4; i++)
        aFr[i] = *(const half8*)(&sA[cur][aOff[s][i]]);
#pragma unroll
      for (int i = 0; i < 4; i++)
#pragma unroll
        for (int j = 0; j < 4; j++)
          acc[i][j] = __builtin_amdgcn_mfma_f32_16x16x32_f16(aFr[i], bCur[s][j], acc[i][j], 0, 0, 0);
    }
#pragma unroll
    for (int s = 0; s < 2; s++)
#pragma unroll
      for (int j = 0; j < 4; j++)
        bCur[s][j] = bNxt[s][j];
  }

  // ---- epilogue: acc -> LDS (frag-major local) -> coalesced dwordx4 stores
  __syncthreads();
  _Float16* cs = &sA[0][0];  // 16384 halves = 32 KB, exactly one C-tile fp16
#pragma unroll
  for (int j = 0; j < 4; j++) {
    int cl = (wc << 6) + (j << 4) + l16;   // local col 0..127
    float bv = bias[nBase + cl];
    int ksl = cl >> 5;
    int sub_hi = ((cl >> 3) & 3) << 4;
    int c7 = cl & 7;
#pragma unroll
    for (int i = 0; i < 4; i++) {
      int m16l = (wr << 2) + i;
#pragma unroll
      for (int r = 0; r < 4; r++) {
        int ml = (quad << 2) + r;          // m & 15
        cs[(((m16l << 2) + ksl) << 9) + ((sub_hi + ml) << 3) + c7] =
            (_Float16)(acc[i][j][r] + bv);
      }
    }
  }
  __syncthreads();
#pragma unroll
  for (int it = 0; it < 8; it++) {
    int cid = (it << 2) + wave;            // 0..31: chunk = (m16l, ksl)
    int m16l = cid >> 2, ksl = cid & 3;
    size_t g = ((size_t)(((mt << 3) + m16l) * 16 + (nt << 2) + ksl) << 9) + (lane << 3);
    *(half8*)(Cf + g) = *(const half8*)(cs + (cid << 9) + (lane << 3));
  }
}

// ------------------- fused GEMM2+GEMM3: h2 never leaves the CU.
__global__ __launch_bounds__(256, 2)
void gemm23(const _Float16* __restrict__ Af, const _Float16* __restrict__ B2,
            const _Float16* __restrict__ B3, const float* __restrict__ bias1,
            const float* __restrict__ bias2, float* __restrict__ out,
            const int* __restrict__ lengths) {
  __shared__ _Float16 sH[32768];   // 64 KB: [m16l(8)][ks(8)][sub(64)][8]
  __shared__ float red[2][128];

  const int tid  = threadIdx.x;
  const int wave = tid >> 6, lane = tid & 63;
  const int wr   = wave >> 1, wc = wave & 1;
  const int quad = lane >> 4, l16 = lane & 15;
  const int mt = blockIdx.x;

  const _Float16* aR[4];
#pragma unroll
  for (int i = 0; i < 4; i++)
    aR[i] = Af + (((size_t)((mt << 3) + (wr << 2) + i) * 16) << 9) + (lane << 3);
  const _Float16* bR[8];
#pragma unroll
  for (int j = 0; j < 8; j++)
    bR[j] = B2 + (((size_t)((wc << 3) + j) * 16) << 9) + (lane << 3);

  floatx4 acc2[4][8] = {};
#pragma unroll 2
  for (int kk = 0; kk < 16; kk++) {
    const size_t ko = (size_t)kk << 9;
    half8 aF[4], bF[8];
#pragma unroll
    for (int i = 0; i < 4; i++) aF[i] = *(const half8*)(aR[i] + ko);
#pragma unroll
    for (int j = 0; j < 8; j++) bF[j] = *(const half8*)(bR[j] + ko);
#pragma unroll
    for (int i = 0; i < 4; i++)
#pragma unroll
      for (int j = 0; j < 8; j++)
        acc2[i][j] = __builtin_amdgcn_mfma_f32_16x16x32_f16(aF[i], bF[j], acc2[i][j], 0, 0, 0);
  }

  // h2 tile -> LDS frag-major, +bias1, relu
#pragma unroll
  for (int j = 0; j < 8; j++) {
    int n = (wc << 7) + (j << 4) + l16;    // h2 col 0..255
    float bv = bias1[n];
    int ks = n >> 5;
    int sub_hi = ((n >> 3) & 3) << 4;
    int c7 = n & 7;
#pragma unroll
    for (int i = 0; i < 4; i++) {
      int m16l = (wr << 2) + i;
#pragma unroll
      for (int r = 0; r < 4; r++) {
        int ml = (quad << 2) + r;
        sH[(((m16l << 3) + ks) << 9) + ((sub_hi + ml) << 3) + c7] =
            (_Float16)fmaxf(acc2[i][j][r] + bv, 0.0f);
      }
    }
  }
  __syncthreads();

  // Phase B: G3 (K=256 from LDS)
  const _Float16* b3R[4];
#pragma unroll
  for (int j = 0; j < 4; j++)
    b3R[j] = B3 + (((size_t)((wc << 2) + j) * 8) << 9) + (lane << 3);

  floatx4 acc3[4][4] = {};
#pragma unroll
  for (int ks = 0; ks < 8; ks++) {
    half8 aF[4], bF[4];
#pragma unroll
    for (int i = 0; i < 4; i++)
      aF[i] = *(const half8*)(sH + (((((wr << 2) + i) << 3) + ks) << 9) + (lane << 3));
#pragma unroll
    for (int j = 0; j < 4; j++) bF[j] = *(const half8*)(b3R[j] + ((size_t)ks << 9));
#pragma unroll
    for (int i = 0; i < 4; i++)
#pragma unroll
      for (int j = 0; j < 4; j++)
        acc3[i][j] = __builtin_amdgcn_mfma_f32_16x16x32_f16(aF[i], bF[j], acc3[i][j], 0, 0, 0);
  }

  // fused relu + ragged-mean pooling (C/D: col=lane&15, row=quad*4+r)
  int b = mt >> 3;
  int validw = lengths[b] - (NGRAM - 1);
  float inv = 1.0f / (float)validw;
  int wBase = ((mt & 7) << 7) + (wr << 6);
#pragma unroll
  for (int j = 0; j < 4; j++) {
    int col = (wc << 6) + (j << 4) + l16;
    float bv = bias2[col];
    float p = 0.0f;
#pragma unroll
    for (int i = 0; i < 4; i++) {
#pragma unroll
      for (int r = 0; r < 4; r++) {
        int w = wBase + (i << 4) + (quad << 2) + r;
        float v = fmaxf(acc3[i][j][r] + bv, 0.0f);
        p += (w < validw) ? v : 0.0f;
      }
    }
    p *= inv;
    p += __shfl_xor(p, 16, 64);
    p += __shfl_xor(p, 32, 64);
    if (quad == 0) red[wr][col] = p;
  }
  __syncthreads();
  if (tid < 128) atomicAdd(out + b * H2D + tid, red[0][tid] + red[1][tid]);
}

// ---------------------------------------------------------------- launcher
extern "C" void kernel_launch(void* const* d_in, const int* in_sizes, int n_in,
                              void* d_out, int out_size, void* d_ws, size_t ws_size,
                              hipStream_t stream) {
  const int*   x       = (const int*)d_in[0];
  const int*   lengths = (const int*)d_in[1];
  const float* table   = (const float*)d_in[2];
  const float* W_slide = (const float*)d_in[3];
  const float* b_slide = (const float*)d_in[4];
  const float* W1      = (const float*)d_in[5];
  const float* b1      = (const float*)d_in[6];
  const float* W2      = (const float*)d_in[7];
  const float* b2      = (const float*)d_in[8];
  float* out = (float*)d_out;

  // workspace (halves). emb +4096 pad: tail windows read past logical end
  // (finite poison * masked rows, see pooling mask).
  _Float16* ws  = (_Float16*)d_ws;
  _Float16* emb = ws;                                   // 64*1024*304
  _Float16* Bf1 = emb + (size_t)MTOT * EMB_P + 4096;    // 512*1536 frag-major
  _Float16* Bf2 = Bf1 + (size_t)H0 * K1P;               // 256*512  frag-major
  _Float16* Bf3 = Bf2 + (size_t)H1D * H0;               // 128*256  frag-major
  _Float16* h1f = Bf3 + (size_t)H2D * H1D;              // 65536*512 frag-major

  prep_kernel<<<GATHER_BLOCKS + WPREP_BLOCKS, 256, 0, stream>>>(
      x, table, emb, out, W_slide, W1, W2, Bf1, Bf2, Bf3);
  // L1: win @ W_slide + b_slide -> h1f (frag-major)
  gemm1<<<(MTOT / 128) * (H0 / 128), 256, 0, stream>>>(emb, Bf1, b_slide, h1f);
  // L2+L3 fused: relu(h1@W1+b1) -> LDS -> relu(.@W2+b2) -> masked-mean pool
  gemm23<<<MTOT / 128, 256, 0, stream>>>(h1f, Bf2, Bf3, b1, b2, out, lengths);
}